// Round 10
// baseline (313.066 us; speedup 1.0000x reference)
//
#include <hip/hip_runtime.h>

#define NU 50000
#define NE 100000
#define NN 150000          // NU + NE
#define DD 64
#define EUI 1500000

#define TPB 256
#define NBLK 2048          // edge-stride kernels
#define NSB 586            // ceil(NN/256) scan1 blocks
#define NS23 147           // ceil(NN/1024) scan23 blocks
#define NXB 2344           // ceil(NN/64) xw tiles
#define NBF2 9375          // NN/16: k_fused blocks (4 waves x 4 nodes each)
#define NSC 9375           // NN*DD/4/256: k_scale blocks (exact)

#define CSTR 32            // cnt stride: one counter per 128-B line

// workspace layout (units: 4-byte words)
#define XWB_OFF    0ull          // 4,800,000 words: xW in bf16 (row = 32 dwords)
#define PD_OFF     4800000ull    // 1,500,000 u32: (rank<<18)|dst per edge
#define SSRC_OFF   6300000ull    // 1,500,000 i32: src sorted by dst
#define CNT_OFF    7800000ull    // 4,800,000 i32 (150,000 counters, stride 32)
#define ROWPTR_OFF 12600000ull   // 150,001 i32
#define BSUM_OFF   12750004ull   // 586 i32
#define PSUM_OFF   12750590ull   // 9,375 f32
#define SCAL_OFF   12760000ull   // [0] = sum(exp(logits))
// total ~12.76M words = 51.0 MB

// f32 -> bf16 RNE pack of two values into one dword (a = low/even dim)
__device__ __forceinline__ unsigned bfpack(float a, float b) {
  unsigned ua = __float_as_uint(a);
  ua = (ua + 0x7fffu + ((ua >> 16) & 1u)) >> 16;
  unsigned ub = __float_as_uint(b);
  ub = (ub + 0x7fffu + ((ub >> 16) & 1u)) & 0xffff0000u;
  return (ua & 0xffffu) | ub;
}

// x + dpp_perm(x) on the VALU pipe (ctrl must be an immediate -> template).
template <int CTRL>
__device__ __forceinline__ float dpp_add(float x) {
  int y = __builtin_amdgcn_update_dpp(0, __float_as_int(x), CTRL, 0xF, 0xF, false);
  return x + __int_as_float(y);
}
// full sum across a 16-lane DPP row: +ror4, +ror8, then quad xor1, xor2.
__device__ __forceinline__ float row16_sum(float x) {
  x = dpp_add<0x124>(x);  // row_ror:4
  x = dpp_add<0x128>(x);  // row_ror:8
  x = dpp_add<0xB1>(x);   // quad_perm [1,0,3,2]  (xor 1)
  x = dpp_add<0x4E>(x);   // quad_perm [2,3,0,1]  (xor 2)
  return x;
}

// ---------------- xW = concat(user_table[uidx], entity_table[iidx]) @ W ------
// LDS-tiled 64x64x64 f32 GEMM; kc loop deliberately NOT unrolled (full unroll
// hoisted all 64 ds_read_b128 -> VGPR 232, occupancy 10%, 88 us in round 6).
__global__ __launch_bounds__(TPB) void k_xw(const int* __restrict__ uidx,
                                            const int* __restrict__ iidx,
                                            const float* __restrict__ ut,
                                            const float* __restrict__ et,
                                            const float* __restrict__ W,
                                            unsigned* __restrict__ xwb) {
  __shared__ float Ws[DD * DD];   // [k][c]
  __shared__ float Xs[64 * 68];   // [r][k], padded stride 68
  const int t = threadIdx.x;
  {
    const float4* W4 = (const float4*)W;
    float4* Ws4 = (float4*)Ws;
#pragma unroll
    for (int i = 0; i < 4; ++i) Ws4[t + i * TPB] = W4[t + i * TPB];
  }
  {
    const int rl = t >> 2, ch = t & 3;   // 4 threads per row, 4 float4 each
    int row = blockIdx.x * 64 + rl;
    if (row >= NN) row = NN - 1;         // clamp; stores guarded below
    const float4* s4 = (const float4*)((row < NU)
        ? ut + (size_t)uidx[row] * DD
        : et + (size_t)iidx[row - NU] * DD);
    float4* x4 = (float4*)(Xs + rl * 68);
#pragma unroll
    for (int j = 0; j < 4; ++j) x4[ch + 4 * j] = s4[ch + 4 * j];
  }
  __syncthreads();
  const int q = t & 15, g = t >> 4;      // col quad, row group (4 rows)
  float4 acc[4] = {{0,0,0,0},{0,0,0,0},{0,0,0,0},{0,0,0,0}};
  const float* __restrict__ wsq = Ws + 4 * q;
  const float* __restrict__ xsg = Xs + (4 * g) * 68;
#pragma unroll 1
  for (int kc = 0; kc < 16; ++kc) {
    const float4 w0 = *(const float4*)(wsq + (4 * kc + 0) * DD);
    const float4 w1 = *(const float4*)(wsq + (4 * kc + 1) * DD);
    const float4 w2 = *(const float4*)(wsq + (4 * kc + 2) * DD);
    const float4 w3 = *(const float4*)(wsq + (4 * kc + 3) * DD);
#pragma unroll
    for (int i = 0; i < 4; ++i) {
      const float4 x = *(const float4*)(xsg + i * 68 + 4 * kc);
      acc[i].x = fmaf(x.x, w0.x, acc[i].x);
      acc[i].y = fmaf(x.x, w0.y, acc[i].y);
      acc[i].z = fmaf(x.x, w0.z, acc[i].z);
      acc[i].w = fmaf(x.x, w0.w, acc[i].w);
      acc[i].x = fmaf(x.y, w1.x, acc[i].x);
      acc[i].y = fmaf(x.y, w1.y, acc[i].y);
      acc[i].z = fmaf(x.y, w1.z, acc[i].z);
      acc[i].w = fmaf(x.y, w1.w, acc[i].w);
      acc[i].x = fmaf(x.z, w2.x, acc[i].x);
      acc[i].y = fmaf(x.z, w2.y, acc[i].y);
      acc[i].z = fmaf(x.z, w2.z, acc[i].z);
      acc[i].w = fmaf(x.z, w2.w, acc[i].w);
      acc[i].x = fmaf(x.w, w3.x, acc[i].x);
      acc[i].y = fmaf(x.w, w3.y, acc[i].y);
      acc[i].z = fmaf(x.w, w3.z, acc[i].z);
      acc[i].w = fmaf(x.w, w3.w, acc[i].w);
    }
  }
#pragma unroll
  for (int i = 0; i < 4; ++i) {
    const int row = blockIdx.x * 64 + 4 * g + i;
    if (row < NN) {
      uint2 p;
      p.x = bfpack(acc[i].x, acc[i].y);
      p.y = bfpack(acc[i].z, acc[i].w);
      ((uint2*)(xwb + (size_t)row * 32))[q] = p;
    }
  }
}

// ---------------- histogram of dst + packed (rank<<18)|dst --------------------
// cnt stride = 32 ints: one counter per 128-B line. Round-9 evidence: packed
// counters -> ~320 atomics/line -> cross-XCD line ping-pong, 63 us at 0.6%
// VALU. Line-exclusive counters cut per-line traffic to ~10.
__global__ __launch_bounds__(TPB) void k_hist(const int* __restrict__ ei,
                                              int* __restrict__ cnt,
                                              unsigned* __restrict__ pd) {
  for (int e = blockIdx.x * TPB + threadIdx.x; e < EUI; e += gridDim.x * TPB) {
    const int dst = ei[EUI + e];
    const unsigned r = (unsigned)atomicAdd(&cnt[(size_t)dst * CSTR], 1);
    pd[e] = (r << 18) | (unsigned)dst;
  }
}

// ---------------- scan stage 1: per-block exclusive + block sums --------------
__global__ __launch_bounds__(TPB) void k_scan1(int* __restrict__ cnt,
                                               int* __restrict__ bsum) {
  __shared__ int sh[TPB];
  const int t = threadIdx.x;
  const int i = blockIdx.x * TPB + t;
  const int v = (i < NN) ? cnt[(size_t)i * CSTR] : 0;
  sh[t] = v;
  __syncthreads();
#pragma unroll
  for (int off = 1; off < TPB; off <<= 1) {
    int add = (t >= off) ? sh[t - off] : 0;
    __syncthreads();
    sh[t] += add;
    __syncthreads();
  }
  if (i < NN) cnt[(size_t)i * CSTR] = sh[t] - v;
  if (t == TPB - 1) bsum[blockIdx.x] = sh[t];
}

// ---------------- scan stages 2+3 merged --------------------------------------
__global__ __launch_bounds__(1024) void k_scan23(const int* __restrict__ excl,
                                                 const int* __restrict__ bsum,
                                                 int* __restrict__ rowptr) {
  __shared__ int sh[1024];
  const int t = threadIdx.x;
  const int v = (t < NSB) ? bsum[t] : 0;
  sh[t] = v;
  __syncthreads();
#pragma unroll
  for (int off = 1; off < 1024; off <<= 1) {
    int add = (t >= off) ? sh[t - off] : 0;
    __syncthreads();
    sh[t] += add;
    __syncthreads();
  }
  const int boff = sh[t] - v;
  __syncthreads();
  sh[t] = boff;
  __syncthreads();
  const int i = blockIdx.x * 1024 + t;
  if (i < NN) rowptr[i] = excl[(size_t)i * CSTR] + sh[i >> 8];
  if (i == 0) rowptr[NN] = EUI;
}

// ---------------- CSR fill (no atomics: p = rowptr[dst] + rank) ---------------
// Non-temporal scatter: bypass the XCD L2 so random 4-B writes don't cause
// cross-XCD line ownership migration (round-5: ~8x write amplification).
__global__ __launch_bounds__(TPB) void k_fill(const int* __restrict__ ei,
                                              const unsigned* __restrict__ pd,
                                              const int* __restrict__ rowptr,
                                              int* __restrict__ ssrc) {
  for (int e = blockIdx.x * TPB + threadIdx.x; e < EUI; e += gridDim.x * TPB) {
    const unsigned p = pd[e];
    __builtin_nontemporal_store(ei[e], &ssrc[rowptr[p & 0x3ffffu] + (int)(p >> 18)]);
  }
}

// ---------------- fused logits+exp+aggregate (bf16, DPP reduce) ---------------
// 16 lanes per node (= one DPP row), 4 nodes per wave, 2 edges per group per
// iteration. Unnormalized: out[n] = sum_e exp(leaky(dot)) * xW[src];
// psum[block] = partial sum of exp (softmax shift-invariant, |logit| < ~1).
__global__ __launch_bounds__(TPB) void k_fused(const int* __restrict__ rowptr,
                                               const int* __restrict__ ssrc,
                                               const unsigned* __restrict__ xwb,
                                               float* __restrict__ out,
                                               float* __restrict__ psum) {
  const int lane = threadIdx.x & 63;
  const int wv = threadIdx.x >> 6;
  const int sub = lane >> 4;   // node slot 0..3 (DPP row)
  const int q = lane & 15;     // dim quad 0..15
  const int n = blockIdx.x * 16 + wv * 4 + sub;  // < NN (NN == 16*NBF2)
  const uint2* __restrict__ x2 = (const uint2*)xwb;  // row stride 16 uint2
  const uint2 dv = x2[(size_t)n * 16 + q];
  const float vd0 = __uint_as_float(dv.x << 16);
  const float vd1 = __uint_as_float(dv.x & 0xffff0000u);
  const float vd2 = __uint_as_float(dv.y << 16);
  const float vd3 = __uint_as_float(dv.y & 0xffff0000u);
  const int b = rowptr[n], en = rowptr[n + 1];
  float a0 = 0.f, a1 = 0.f, a2 = 0.f, a3 = 0.f, wacc = 0.f;
  for (int it = b;; it += 2) {
    const bool act0 = it < en;
    if (!__any(act0)) break;
    const bool act1 = it + 1 < en;
    const int s0 = ssrc[act0 ? it : b];
    const int s1 = ssrc[act1 ? it + 1 : b];
    const uint2 sv0 = x2[(size_t)s0 * 16 + q];
    const uint2 sv1 = x2[(size_t)s1 * 16 + q];
    const float u0 = __uint_as_float(sv0.x << 16);
    const float u1 = __uint_as_float(sv0.x & 0xffff0000u);
    const float u2 = __uint_as_float(sv0.y << 16);
    const float u3 = __uint_as_float(sv0.y & 0xffff0000u);
    const float t0 = __uint_as_float(sv1.x << 16);
    const float t1 = __uint_as_float(sv1.x & 0xffff0000u);
    const float t2 = __uint_as_float(sv1.y << 16);
    const float t3 = __uint_as_float(sv1.y & 0xffff0000u);
    float p0 = vd0 * u0;
    p0 = fmaf(vd1, u1, p0);
    p0 = fmaf(vd2, u2, p0);
    p0 = fmaf(vd3, u3, p0);
    float p1 = vd0 * t0;
    p1 = fmaf(vd1, t1, p1);
    p1 = fmaf(vd2, t2, p1);
    p1 = fmaf(vd3, t3, p1);
    p0 = row16_sum(p0);
    p1 = row16_sum(p1);
    const float l0 = (p0 > 0.f) ? p0 : 0.2f * p0;
    const float l1 = (p1 > 0.f) ? p1 : 0.2f * p1;
    float w0 = __expf(l0);
    float w1 = __expf(l1);
    if (!act0) w0 = 0.f;
    if (!act1) w1 = 0.f;
    a0 = fmaf(w0, u0, a0);
    a1 = fmaf(w0, u1, a1);
    a2 = fmaf(w0, u2, a2);
    a3 = fmaf(w0, u3, a3);
    a0 = fmaf(w1, t0, a0);
    a1 = fmaf(w1, t1, a1);
    a2 = fmaf(w1, t2, a2);
    a3 = fmaf(w1, t3, a3);
    wacc += w0 + w1;   // group-uniform (same w on all 16 lanes)
  }
  float4 r = {a0, a1, a2, a3};
  ((float4*)(out + (size_t)n * DD))[q] = r;   // full row, no epilogue combine
  // block partial of sum(exp): one lane per group (q==0) holds wacc
  __shared__ float sm[16];
  if (q == 0) sm[wv * 4 + sub] = wacc;
  __syncthreads();
  if (threadIdx.x == 0) {
    float s = 0.f;
#pragma unroll
    for (int i = 0; i < 16; ++i) s += sm[i];
    psum[blockIdx.x] = s;
  }
}

// ---------------- total exp-sum -----------------------------------------------
__global__ __launch_bounds__(TPB) void k_rsum(const float* __restrict__ psum,
                                              float* __restrict__ scal) {
  float s = 0.f;
  for (int i = threadIdx.x; i < NBF2; i += TPB) s += psum[i];
#pragma unroll
  for (int off = 32; off; off >>= 1) s += __shfl_xor(s, off, 64);
  __shared__ float sm[4];
  if ((threadIdx.x & 63) == 0) sm[threadIdx.x >> 6] = s;
  __syncthreads();
  if (threadIdx.x == 0) scal[0] = sm[0] + sm[1] + sm[2] + sm[3];
}

// ---------------- out = relu(out / sumexp) ------------------------------------
__global__ __launch_bounds__(TPB) void k_scale(float* __restrict__ out,
                                               const float* __restrict__ scal) {
  const float inv = 1.0f / scal[0];
  const int i = blockIdx.x * TPB + threadIdx.x;
  float4* o4 = (float4*)out;
  float4 v = o4[i];
  v.x = fmaxf(v.x * inv, 0.f);
  v.y = fmaxf(v.y * inv, 0.f);
  v.z = fmaxf(v.z * inv, 0.f);
  v.w = fmaxf(v.w * inv, 0.f);
  o4[i] = v;
}

extern "C" void kernel_launch(void* const* d_in, const int* in_sizes, int n_in,
                              void* d_out, int out_size, void* d_ws, size_t ws_size,
                              hipStream_t stream) {
  const int* uidx = (const int*)d_in[0];
  const int* iidx = (const int*)d_in[1];
  const int* ei_ui = (const int*)d_in[2];
  // d_in[3], d_in[4], d_in[8] (KG graph, W_r): dead code in the reference
  // (x_kg is added into x, then x is fully overwritten by relu(x_ui)).
  const float* ut = (const float*)d_in[5];
  const float* et = (const float*)d_in[6];
  const float* W = (const float*)d_in[7];

  float* out = (float*)d_out;
  float* ws = (float*)d_ws;
  unsigned* xwb = (unsigned*)(ws + XWB_OFF);
  unsigned* pd = (unsigned*)(ws + PD_OFF);
  int* ssrc = (int*)(ws + SSRC_OFF);
  int* cnt = (int*)(ws + CNT_OFF);
  int* rowptr = (int*)(ws + ROWPTR_OFF);
  int* bsum = (int*)(ws + BSUM_OFF);
  float* psum = ws + PSUM_OFF;
  float* scal = ws + SCAL_OFF;

  (void)hipMemsetAsync(cnt, 0, (size_t)NN * CSTR * sizeof(int), stream);

  k_xw<<<NXB, TPB, 0, stream>>>(uidx, iidx, ut, et, W, xwb);
  k_hist<<<NBLK, TPB, 0, stream>>>(ei_ui, cnt, pd);
  k_scan1<<<NSB, TPB, 0, stream>>>(cnt, bsum);
  k_scan23<<<NS23, 1024, 0, stream>>>(cnt, bsum, rowptr);
  k_fill<<<NBLK, TPB, 0, stream>>>(ei_ui, pd, rowptr, ssrc);
  k_fused<<<NBF2, TPB, 0, stream>>>(rowptr, ssrc, xwb, out, psum);
  k_rsum<<<1, TPB, 0, stream>>>(psum, scal);
  k_scale<<<NSC, TPB, 0, stream>>>(out, scal);
}